// Round 3
// baseline (108.933 us; speedup 1.0000x reference)
//
#include <hip/hip_runtime.h>

#define NP 320                  // particles
#define HD 32                   // hidden dim
#define MT 4                    // trajectories
#define LS 6                    // snapshots
#define BB (MT * (LS - 1))      // 20 batch elements
#define NEC (2 * MT)            // energy configs (telescoped boundaries)
#define SIG2 0.01f              // sigma^2
#define L2E2 2.8853900817779268f  // 2*log2(e)

#define PAIR_ROWS (BB * NP)     // 6400
#define EN_ROWS   (NEC * NP)    // 2560
#define ROWS      (PAIR_ROWS + EN_ROWS)  // 8960
#define WPB 4                   // waves (rows) per block

__device__ __forceinline__ float fexp2(float x) { return __builtin_amdgcn_exp2f(x); }
__device__ __forceinline__ float frcp(float x)  { return __builtin_amdgcn_rcpf(x); }

// --------------------------------------------------------------------------
// One WAVE per row. Rows [0, PAIR_ROWS): pairwise drift/laplacian over
// X_curr. Rows [PAIR_ROWS, ROWS): telescoped boundary energies.
// PAIR_ROWS % WPB == 0, so every block is branch-uniform.
// Each lane handles 5 j's (320 = 5*64); all reductions are in-wave shfl.
//
// tanh(x) = 1 - 2r,  r = 1/(exp2(L2E2*x)+1)
//   1 - t^2   = 4(r - r^2) = 4u
//   t*(1-t^2) = 4u(1-2r)
// --------------------------------------------------------------------------
__global__ __launch_bounds__(64 * WPB) void main_kernel(
    const float* __restrict__ data,      // (MT, LS, NP, 2)
    const float* __restrict__ t_snap,    // (LS,)
    const float* __restrict__ V_w1,      // (2, HD)
    const float* __restrict__ V_b1,      // (HD,)
    const float* __restrict__ V_w2,      // (HD,)
    const float* __restrict__ V_b2,      // (1,)
    const float* __restrict__ Phi_w1,    // (HD,)
    const float* __restrict__ Phi_b1,    // (HD,)
    const float* __restrict__ Phi_w2,    // (HD,)
    const float* __restrict__ Phi_b2,    // (1,)
    float* __restrict__ ws)              // [PAIR_ROWS] pair partials + [EN_ROWS] energy partials
{
    __shared__ float4 sC[HD];            // wL2E2, bL2E2, 4*w*w2, -8*w^2*w2
    __shared__ float  sW2[HD];           // Phi_w2

    const int tid  = threadIdx.x;
    const int lane = tid & 63;
    const int row  = blockIdx.x * WPB + (tid >> 6);

    if (tid < HD) {
        float w  = Phi_w1[tid];
        float bb = Phi_b1[tid];
        float w2 = Phi_w2[tid];
        sC[tid]  = make_float4(w * L2E2, bb * L2E2, 4.0f * w * w2, -8.0f * w * w * w2);
        sW2[tid] = w2;
    }
    __syncthreads();

    if (row < PAIR_ROWS) {
        // ---------------- pairwise drift + laplacian ----------------
        const int b = row / NP;
        const int i = row - b * NP;
        const int m = b / (LS - 1);
        const int l = b - m * (LS - 1);
        const float2* X = (const float2*)(data + ((size_t)m * LS + l) * NP * 2);
        const float2 xi = X[i];

        float gx = 0.0f, gy = 0.0f, lp = 0.0f;
        #pragma unroll 1
        for (int k = 0; k < NP / 64; ++k) {
            const int j = lane + 64 * k;
            const float2 xj = X[j];
            const float d0 = xi.x - xj.x;
            const float d1 = xi.y - xj.y;
            const float dist = sqrtf(d0 * d0 + d1 * d1);
            const float inv  = frcp(fmaxf(dist, 1e-10f));
            float dphi = 0.0f, d2phi = 0.0f;
            #pragma unroll
            for (int h = 0; h < HD; ++h) {
                float4 c = sC[h];
                float e = fexp2(fmaf(dist, c.x, c.y));
                float r = frcp(e + 1.0f);
                float u = fmaf(-r, r, r);            // r - r^2
                float s = fmaf(-2.0f, r, 1.0f);      // 1 - 2r
                dphi  = fmaf(u,     c.z, dphi);      // Phi'
                d2phi = fmaf(u * s, c.w, d2phi);     // Phi''
            }
            float t0  = dphi * inv;
            float gxk = t0 * d0;
            float gyk = t0 * d1;
            float lpk = d2phi + t0;                  // d=2: +(d-1)/r * Phi'
            if (j == i) { gxk = 0.0f; gyk = 0.0f; lpk = 0.0f; }
            gx += gxk; gy += gyk; lp += lpk;
        }
        #pragma unroll
        for (int off = 32; off; off >>= 1) {
            gx += __shfl_down(gx, off, 64);
            gy += __shfl_down(gy, off, 64);
            lp += __shfl_down(lp, off, 64);
        }

        // one-body grad V / lap V at x_i, lanes 0..31 (h = lane)
        float gvx = 0.0f, gvy = 0.0f, lv = 0.0f;
        if (lane < HD) {
            float w0 = V_w1[lane];
            float w1 = V_w1[HD + lane];
            float z  = fmaf(xi.x, w0, fmaf(xi.y, w1, V_b1[lane]));
            float e  = fexp2(z * L2E2);
            float r  = frcp(e + 1.0f);
            float u  = fmaf(-r, r, r);
            float s  = fmaf(-2.0f, r, 1.0f);
            float v2 = V_w2[lane];
            float u4 = 4.0f * u * v2;
            gvx = u4 * w0;
            gvy = u4 * w1;
            lv  = -8.0f * u * s * v2 * (w0 * w0 + w1 * w1);
            #pragma unroll
            for (int off = 16; off; off >>= 1) {
                gvx += __shfl_xor(gvx, off, 64);
                gvy += __shfl_xor(gvy, off, 64);
                lv  += __shfl_xor(lv,  off, 64);
            }
        }

        if (lane == 0) {
            const float invN = 1.0f / (float)NP;
            float dx = -gvx - gx * invN;
            float dy = -gvy - gy * invN;
            float lap_sum = lv + lp * invN;
            float dt = t_snap[l + 1] - t_snap[l];
            ws[row] = dt * (dx * dx + dy * dy) * invN
                    + SIG2 * dt * lap_sum * invN;
        }
    } else {
        // ---------------- telescoped boundary energies ----------------
        const int erow = row - PAIR_ROWS;
        const int c    = erow / NP;
        const int i    = erow - c * NP;
        const int m    = c >> 1;
        const int l    = (c & 1) ? (LS - 1) : 0;
        const float coef = (c & 1) ? 1.0f : -1.0f;
        const float2* X = (const float2*)(data + ((size_t)m * LS + l) * NP * 2);
        const float2 xi = X[i];

        float S = 0.0f;                       // sum_{j!=i} sum_h w2[h]*r
        #pragma unroll 1
        for (int k = 0; k < NP / 64; ++k) {
            const int j = lane + 64 * k;
            const float2 xj = X[j];
            const float d0 = xi.x - xj.x;
            const float d1 = xi.y - xj.y;
            const float dist = sqrtf(d0 * d0 + d1 * d1);
            float rs = 0.0f;
            #pragma unroll
            for (int h = 0; h < HD; ++h) {
                float4 cc = sC[h];
                float e = fexp2(fmaf(dist, cc.x, cc.y));
                float r = frcp(e + 1.0f);
                rs = fmaf(sW2[h], r, rs);
            }
            if (j == i) rs = 0.0f;
            S += rs;
        }
        #pragma unroll
        for (int off = 32; off; off >>= 1) S += __shfl_down(S, off, 64);

        // V(x_i) on lanes 0..31, plus wave-uniform sums of V_w2 / Phi_w2
        float vr = 0.0f, v2s = 0.0f, w2s = 0.0f;
        if (lane < HD) {
            float w0 = V_w1[lane];
            float w1 = V_w1[HD + lane];
            float z  = fmaf(xi.x, w0, fmaf(xi.y, w1, V_b1[lane]));
            float e  = fexp2(z * L2E2);
            float r  = frcp(e + 1.0f);
            float v2 = V_w2[lane];
            vr  = v2 * r;
            v2s = v2;
            w2s = sW2[lane];
            #pragma unroll
            for (int off = 16; off; off >>= 1) {
                vr  += __shfl_xor(vr,  off, 64);
                v2s += __shfl_xor(v2s, off, 64);
                w2s += __shfl_xor(w2s, off, 64);
            }
        }

        if (lane == 0) {
            const float invN = 1.0f / (float)NP;
            float v = V_b2[0] + v2s - 2.0f * vr;                     // V(x_i)
            float P = (float)(NP - 1) * (w2s + Phi_b2[0]) - 2.0f * S; // row Phi sum
            ws[PAIR_ROWS + erow] = coef * (v * invN + P * invN * invN);
        }
    }
}

// --------------------------------------------------------------------------
// Reduce: S0 = sum pair partials, S1 = sum energy partials (signs folded),
// out = ((S0 - 2*S1)/B)^2
// --------------------------------------------------------------------------
__global__ __launch_bounds__(1024) void reduce_kernel(
    const float* __restrict__ ws, float* __restrict__ out)
{
    __shared__ float sR[16][2];
    const int tid = threadIdx.x;
    float a0 = 0.0f, a1 = 0.0f;
    for (int idx = tid; idx < PAIR_ROWS; idx += 1024) a0 += ws[idx];
    for (int idx = tid; idx < EN_ROWS; idx += 1024)   a1 += ws[PAIR_ROWS + idx];
    #pragma unroll
    for (int off = 32; off; off >>= 1) {
        a0 += __shfl_down(a0, off, 64);
        a1 += __shfl_down(a1, off, 64);
    }
    const int lane = tid & 63, wid = tid >> 6;
    if (lane == 0) { sR[wid][0] = a0; sR[wid][1] = a1; }
    __syncthreads();
    if (tid == 0) {
        float S0 = 0.0f, S1 = 0.0f;
        #pragma unroll
        for (int w = 0; w < 16; ++w) { S0 += sR[w][0]; S1 += sR[w][1]; }
        float res = (S0 - 2.0f * S1) / (float)BB;
        out[0] = res * res;
    }
}

extern "C" void kernel_launch(void* const* d_in, const int* in_sizes, int n_in,
                              void* d_out, int out_size, void* d_ws, size_t ws_size,
                              hipStream_t stream) {
    const float* data    = (const float*)d_in[0];
    const float* t_snap  = (const float*)d_in[1];
    const float* V_w1    = (const float*)d_in[2];
    const float* V_b1    = (const float*)d_in[3];
    const float* V_w2    = (const float*)d_in[4];
    const float* V_b2    = (const float*)d_in[5];
    const float* Phi_w1  = (const float*)d_in[6];
    const float* Phi_b1  = (const float*)d_in[7];
    const float* Phi_w2  = (const float*)d_in[8];
    const float* Phi_b2  = (const float*)d_in[9];
    float* ws  = (float*)d_ws;
    float* out = (float*)d_out;

    main_kernel<<<ROWS / WPB, 64 * WPB, 0, stream>>>(
        data, t_snap, V_w1, V_b1, V_w2, V_b2, Phi_w1, Phi_b1, Phi_w2, Phi_b2, ws);

    reduce_kernel<<<1, 1024, 0, stream>>>(ws, out);
}